// Round 1
// baseline (308.460 us; speedup 1.0000x reference)
//
#include <hip/hip_runtime.h>
#include <math.h>

// ---------------------------------------------------------------------------
// LightweightEncoder: correctness-first multi-kernel implementation.
// Shapes: x_init [8,3,1024,1024] f32.
//   x   = conv(x_init, sample_w/sigma, b, s=4, p=0)      -> [8,3,256,256]
//   ctx: h = x_init; 4x { conv(relu(bn_i(h)), 3x3, s=2, p=1) }
//        h2 (layer2 out) [8,3,128,128], h3 (layer3 out) [8,3,64,64]
//   p1  = conv(x,  2x2, s=2) -> [8,3,128,128]; p2 = conv(p1,...) -> [8,3,64,64]
//   final select + soft VQ at 256 res; histogram/count reductions.
// ---------------------------------------------------------------------------

#define NB 8
#define BN_EPS 1.001f   // 1 + eps

// ---- ws layout (floats) ----
// [0..143]          scaled sample weights
// ints at +256      acc[0..7]=hist, acc[8..10]=cond counts
// +512              bufX   1,572,864
// then              bufH0  6,291,456
//                   bufH1  1,572,864
//                   bufH2    393,216
//                   bufH3     98,304
//                   bufP1    393,216
//                   bufP2     98,304

// K0: sigma via 3x3 Gram closed-form eigenvalue (double), scale weights, zero acc
__global__ void k_sigma_scale(const float* __restrict__ sw,
                              float* __restrict__ w_scaled,
                              int* __restrict__ acc) {
    __shared__ float s_sigma;
    int t = threadIdx.x;
    if (t == 0) {
        double G[3][3];
        for (int i = 0; i < 3; i++)
            for (int j = 0; j < 3; j++) {
                double s = 0.0;
                for (int k = 0; k < 48; k++)
                    s += (double)sw[i * 48 + k] * (double)sw[j * 48 + k];
                G[i][j] = s;
            }
        double p1 = G[0][1]*G[0][1] + G[0][2]*G[0][2] + G[1][2]*G[1][2];
        double q  = (G[0][0] + G[1][1] + G[2][2]) / 3.0;
        double p2 = (G[0][0]-q)*(G[0][0]-q) + (G[1][1]-q)*(G[1][1]-q)
                  + (G[2][2]-q)*(G[2][2]-q) + 2.0 * p1;
        double eig;
        if (p2 < 1e-30) {
            eig = q;
        } else {
            double p = sqrt(p2 / 6.0);
            double B[3][3];
            for (int i = 0; i < 3; i++)
                for (int j = 0; j < 3; j++)
                    B[i][j] = (G[i][j] - (i == j ? q : 0.0)) / p;
            double detB = B[0][0]*(B[1][1]*B[2][2]-B[1][2]*B[2][1])
                        - B[0][1]*(B[1][0]*B[2][2]-B[1][2]*B[2][0])
                        + B[0][2]*(B[1][0]*B[2][1]-B[1][1]*B[2][0]);
            double r = detB / 2.0;
            r = r < -1.0 ? -1.0 : (r > 1.0 ? 1.0 : r);
            double phi = acos(r) / 3.0;
            eig = q + 2.0 * p * cos(phi);
        }
        s_sigma = (float)sqrt(eig);
    }
    __syncthreads();
    float sig = s_sigma;
    for (int i = t; i < 144; i += blockDim.x) w_scaled[i] = sw[i] / sig;
    if (t < 11) acc[t] = 0;
}

// K1: sample conv 4x4 stride4 pad0, 3->3ch, float4 loads
__global__ void k_sample(const float* __restrict__ xin,
                         const float* __restrict__ w,
                         const float* __restrict__ bias,
                         float* __restrict__ out) {
    __shared__ float sw[144];
    __shared__ float sb[3];
    int t = threadIdx.x;
    if (t < 144) sw[t] = w[t];
    if (t < 3)   sb[t] = bias[t];
    __syncthreads();
    int gid = blockIdx.x * 256 + t;            // b*65536 + y*256 + x
    int xc = gid & 255, y = (gid >> 8) & 255, b = gid >> 16;
    float a0 = sb[0], a1 = sb[1], a2 = sb[2];
    for (int c = 0; c < 3; c++) {
        const float* base = xin + (((size_t)(b * 3 + c) * 1024 + (size_t)y * 4) * 1024) + xc * 4;
        for (int kh = 0; kh < 4; kh++) {
            float4 v = *(const float4*)(base + kh * 1024);
            const float* w0 = &sw[(0 * 3 + c) * 16 + kh * 4];
            const float* w1 = &sw[(1 * 3 + c) * 16 + kh * 4];
            const float* w2 = &sw[(2 * 3 + c) * 16 + kh * 4];
            a0 += w0[0]*v.x + w0[1]*v.y + w0[2]*v.z + w0[3]*v.w;
            a1 += w1[0]*v.x + w1[1]*v.y + w1[2]*v.z + w1[3]*v.w;
            a2 += w2[0]*v.x + w2[1]*v.y + w2[2]*v.z + w2[3]*v.w;
        }
    }
    size_t o = (size_t)(b * 3) * 65536 + (y << 8) + xc;
    out[o] = a0; out[o + 65536] = a1; out[o + 131072] = a2;
}

// K2: ctx conv 3x3 stride2 pad1 with BN+ReLU on input (pad AFTER bn/relu -> 0)
__global__ void k_ctx(const float* __restrict__ in, float* __restrict__ out,
                      const float* __restrict__ w, const float* __restrict__ bias,
                      const float* __restrict__ bng, const float* __restrict__ bnb,
                      int inH, int inW) {
    __shared__ float sw[81], sb[3], sinv[3], sbb[3];
    int t = threadIdx.x;
    if (t < 81) sw[t] = w[t];
    if (t < 3) {
        sb[t] = bias[t];
        sinv[t] = bng[t] / sqrtf(BN_EPS);
        sbb[t] = bnb[t];
    }
    __syncthreads();
    int outH = inH >> 1, outW = inW >> 1;
    int gid = blockIdx.x * 256 + t;
    int n = NB * outH * outW;
    if (gid >= n) return;
    int xc = gid % outW;
    int rem = gid / outW;
    int y = rem % outH;
    int b = rem / outH;
    float a0 = sb[0], a1 = sb[1], a2 = sb[2];
    for (int c = 0; c < 3; c++) {
        float inv = sinv[c], bb = sbb[c];
        const float* p = in + (size_t)(b * 3 + c) * inH * inW;
        for (int kh = 0; kh < 3; kh++) {
            int row = 2 * y + kh - 1;
            if (row < 0 || row >= inH) continue;
            for (int kw = 0; kw < 3; kw++) {
                int col = 2 * xc + kw - 1;
                if (col < 0 || col >= inW) continue;
                float v = p[(size_t)row * inW + col];
                v = fmaxf(inv * v + bb, 0.0f);
                int wi = c * 9 + kh * 3 + kw;
                a0 += sw[wi] * v;
                a1 += sw[27 + wi] * v;
                a2 += sw[54 + wi] * v;
            }
        }
    }
    size_t os = (size_t)outH * outW;
    size_t o = (size_t)(b * 3) * os + (size_t)y * outW + xc;
    out[o] = a0; out[o + os] = a1; out[o + 2 * os] = a2;
}

// K3: pool conv 2x2 stride2 pad0
__global__ void k_pool(const float* __restrict__ in, float* __restrict__ out,
                       const float* __restrict__ w, const float* __restrict__ bias,
                       int inH, int inW) {
    __shared__ float sw[36], sb[3];
    int t = threadIdx.x;
    if (t < 36) sw[t] = w[t];
    if (t < 3)  sb[t] = bias[t];
    __syncthreads();
    int outH = inH >> 1, outW = inW >> 1;
    int gid = blockIdx.x * 256 + t;
    int n = NB * outH * outW;
    if (gid >= n) return;
    int xc = gid % outW;
    int rem = gid / outW;
    int y = rem % outH;
    int b = rem / outH;
    float a0 = sb[0], a1 = sb[1], a2 = sb[2];
    for (int c = 0; c < 3; c++) {
        const float* p = in + (size_t)(b * 3 + c) * inH * inW + (size_t)(2 * y) * inW + 2 * xc;
        for (int kh = 0; kh < 2; kh++)
            for (int kw = 0; kw < 2; kw++) {
                float v = p[kh * inW + kw];
                int wi = c * 4 + kh * 2 + kw;
                a0 += sw[wi] * v;
                a1 += sw[12 + wi] * v;
                a2 += sw[24 + wi] * v;
            }
    }
    size_t os = (size_t)outH * outW;
    size_t o = (size_t)(b * 3) * os + (size_t)y * outW + xc;
    out[o] = a0; out[o + os] = a1; out[o + 2 * os] = a2;
}

__device__ __forceinline__ float featf(float h) { return 0.5f * (tanhf(h) + 1.0f); }

// K4: final select + soft VQ at 256 res + cond counts + cond_0 histogram
__global__ void k_final(const float* __restrict__ x, const float* __restrict__ h2,
                        const float* __restrict__ h3, const float* __restrict__ p1,
                        const float* __restrict__ p2, const float* __restrict__ thresh,
                        const float* __restrict__ centers, float* __restrict__ out,
                        int* __restrict__ acc) {
    __shared__ float sc[8];
    __shared__ int sh[11];
    int t = threadIdx.x;
    if (t < 8) sc[t] = centers[t];
    if (t < 11) sh[t] = 0;
    __syncthreads();
    float th1 = thresh[0], th2 = thresh[1];
    int gid = blockIdx.x * 256 + t;            // b*65536 + y*256 + x
    int xc = gid & 255, y = (gid >> 8) & 255, b = gid >> 16;
    int i2 = ((y >> 1) << 7) + (xc >> 1);      // 128-res index
    int i4 = ((y >> 2) << 6) + (xc >> 2);      // 64-res index
    int c0 = 0, c1 = 0, c2 = 0;
    for (int c = 0; c < 3; c++) {
        int pc = b * 3 + c;
        float f1 = featf(h2[(size_t)pc * 16384 + i2]);
        float f2 = featf(h3[(size_t)pc * 4096 + i4]);
        bool cond2 = f2 < th2;
        bool cond1 = (!cond2) && (f1 < th1);
        bool cond0 = !(cond1 || cond2);
        float xv = x[(size_t)pc * 65536 + (y << 8) + xc];
        float xq = cond2 ? p2[(size_t)pc * 4096 + i4]
                         : (cond1 ? p1[(size_t)pc * 16384 + i2] : xv);
        float d[8];
        float dmin = 1e30f;
        for (int k = 0; k < 8; k++) {
            float df = xq - sc[k];
            d[k] = df * df;
            dmin = fminf(dmin, d[k]);
        }
        float se = 0.0f, sn = 0.0f;
        for (int k = 0; k < 8; k++) {
            float e = expf(dmin - d[k]);
            se += e;
            sn += sc[k] * e;
        }
        out[(size_t)pc * 65536 + (y << 8) + xc] = sn / se;
        c0 += cond0; c1 += cond1; c2 += cond2;
        if (cond0) {
            // argmin over (xv - centers)^2, first-min tie-break
            float dd[8];
            float best = 1e30f; int ki = 0;
            for (int k = 0; k < 8; k++) { float df = xv - sc[k]; dd[k] = df * df; }
            for (int k = 0; k < 8; k++) { if (dd[k] < best) { best = dd[k]; ki = k; } }
            atomicAdd(&sh[ki], 1);
        }
    }
    atomicAdd(&sh[8], c0); atomicAdd(&sh[9], c1); atomicAdd(&sh[10], c2);
    __syncthreads();
    if (t < 11 && sh[t] != 0) atomicAdd(&acc[t], sh[t]);
}

// K5: mask_1 histogram at 128 res over p1
__global__ void k_mask1(const float* __restrict__ h2, const float* __restrict__ h3,
                        const float* __restrict__ p1, const float* __restrict__ thresh,
                        const float* __restrict__ centers, int* __restrict__ acc) {
    __shared__ float sc[8];
    __shared__ int sh[8];
    int t = threadIdx.x;
    if (t < 8) { sc[t] = centers[t]; sh[t] = 0; }
    __syncthreads();
    float th1 = thresh[0], th2 = thresh[1];
    int gid = blockIdx.x * 256 + t;            // 8*128*128
    int xc = gid & 127, y = (gid >> 7) & 127, b = gid >> 14;
    int i2 = ((y >> 1) << 6) + (xc >> 1);
    for (int c = 0; c < 3; c++) {
        int pc = b * 3 + c;
        float f1 = featf(h2[(size_t)pc * 16384 + (y << 7) + xc]);
        float f2 = featf(h3[(size_t)pc * 4096 + i2]);
        if (f2 >= th2 && f1 < th1) {
            float v = p1[(size_t)pc * 16384 + (y << 7) + xc];
            float best = 1e30f; int ki = 0;
            for (int k = 0; k < 8; k++) {
                float df = v - sc[k]; float dk = df * df;
                if (dk < best) { best = dk; ki = k; }
            }
            atomicAdd(&sh[ki], 1);
        }
    }
    __syncthreads();
    if (t < 8 && sh[t] != 0) atomicAdd(&acc[t], sh[t]);
}

// K6: mask_2 histogram at 64 res over p2
__global__ void k_mask2(const float* __restrict__ h3, const float* __restrict__ p2,
                        const float* __restrict__ thresh, const float* __restrict__ centers,
                        int* __restrict__ acc) {
    __shared__ float sc[8];
    __shared__ int sh[8];
    int t = threadIdx.x;
    if (t < 8) { sc[t] = centers[t]; sh[t] = 0; }
    __syncthreads();
    float th2 = thresh[1];
    int gid = blockIdx.x * 256 + t;            // 8*64*64
    int xc = gid & 63, y = (gid >> 6) & 63, b = gid >> 12;
    for (int c = 0; c < 3; c++) {
        int pc = b * 3 + c;
        float f2 = featf(h3[(size_t)pc * 4096 + (y << 6) + xc]);
        if (f2 < th2) {
            float v = p2[(size_t)pc * 4096 + (y << 6) + xc];
            float best = 1e30f; int ki = 0;
            for (int k = 0; k < 8; k++) {
                float df = v - sc[k]; float dk = df * df;
                if (dk < best) { best = dk; ki = k; }
            }
            atomicAdd(&sh[ki], 1);
        }
    }
    __syncthreads();
    if (t < 8 && sh[t] != 0) atomicAdd(&acc[t], sh[t]);
}

// K7: finalize scalars
__global__ void k_finalize(const int* __restrict__ acc, float* __restrict__ out2) {
    if (threadIdx.x != 0 || blockIdx.x != 0) return;
    float cnt0 = (float)acc[8], cnt1 = (float)acc[9], cnt2 = (float)acc[10];
    float esti = cnt0 + cnt1 / 4.0f + cnt2 / 16.0f;
    float cr = (1.0f / 16.0f) * esti / (256.0f * 256.0f * 3.0f * 8.0f);
    float cs[8];
    float tot = 0.0f;
    for (int k = 0; k < 8; k++) { cs[k] = (float)acc[k]; tot += cs[k]; }
    float mean = 0.0f;
    for (int k = 0; k < 8; k++) { cs[k] /= tot; mean += cs[k]; }
    mean /= 8.0f;
    float var = 0.0f;
    for (int k = 0; k < 8; k++) { float df = cs[k] - mean; var += df * df; }
    var /= 7.0f;
    out2[0] = cr;
    out2[1] = sqrtf(var);
}

extern "C" void kernel_launch(void* const* d_in, const int* in_sizes, int n_in,
                              void* d_out, int out_size, void* d_ws, size_t ws_size,
                              hipStream_t stream) {
    const float* x_init   = (const float*)d_in[0];
    const float* thresh   = (const float*)d_in[1];
    const float* sample_w = (const float*)d_in[2];
    const float* sample_b = (const float*)d_in[3];
    const float* centers  = (const float*)d_in[4];
    const float* pool1_w  = (const float*)d_in[5];
    const float* pool1_b  = (const float*)d_in[6];
    const float* pool2_w  = (const float*)d_in[7];
    const float* pool2_b  = (const float*)d_in[8];
    const float* ctx_w    = (const float*)d_in[9];   // (4,3,3,3,3)
    const float* ctx_b    = (const float*)d_in[10];  // (4,3)
    const float* bn_g     = (const float*)d_in[11];  // (4,3)
    const float* bn_b     = (const float*)d_in[12];  // (4,3)
    float* out = (float*)d_out;

    float* wsf      = (float*)d_ws;
    float* w_scaled = wsf;
    int*   acc      = (int*)(wsf + 256);
    float* bufX     = wsf + 512;                 // [8,3,256,256]
    float* bufH0    = bufX  + 1572864;           // [8,3,512,512]
    float* bufH1    = bufH0 + 6291456;           // [8,3,256,256]
    float* bufH2    = bufH1 + 1572864;           // [8,3,128,128]
    float* bufH3    = bufH2 + 393216;            // [8,3,64,64]
    float* bufP1    = bufH3 + 98304;             // [8,3,128,128]
    float* bufP2    = bufP1 + 393216;            // [8,3,64,64]

    k_sigma_scale<<<1, 64, 0, stream>>>(sample_w, w_scaled, acc);
    k_sample<<<2048, 256, 0, stream>>>(x_init, w_scaled, sample_b, bufX);
    k_ctx<<<8192, 256, 0, stream>>>(x_init, bufH0, ctx_w,       ctx_b,     bn_g,     bn_b,     1024, 1024);
    k_ctx<<<2048, 256, 0, stream>>>(bufH0,  bufH1, ctx_w + 81,  ctx_b + 3, bn_g + 3, bn_b + 3, 512, 512);
    k_ctx<<<512,  256, 0, stream>>>(bufH1,  bufH2, ctx_w + 162, ctx_b + 6, bn_g + 6, bn_b + 6, 256, 256);
    k_ctx<<<128,  256, 0, stream>>>(bufH2,  bufH3, ctx_w + 243, ctx_b + 9, bn_g + 9, bn_b + 9, 128, 128);
    k_pool<<<512, 256, 0, stream>>>(bufX, bufP1, pool1_w, pool1_b, 256, 256);
    k_pool<<<128, 256, 0, stream>>>(bufP1, bufP2, pool2_w, pool2_b, 128, 128);
    k_final<<<2048, 256, 0, stream>>>(bufX, bufH2, bufH3, bufP1, bufP2, thresh, centers, out, acc);
    k_mask1<<<512, 256, 0, stream>>>(bufH2, bufH3, bufP1, thresh, centers, acc);
    k_mask2<<<128, 256, 0, stream>>>(bufH3, bufP2, thresh, centers, acc);
    k_finalize<<<1, 1, 0, stream>>>(acc, out + 1572864);
}